// Round 15
// baseline (354.708 us; speedup 1.0000x reference)
//
#include <hip/hip_runtime.h>

// Frag2Mol: embed -> encoder(VAE) -> 2x GRU(scan over T=64) -> vocab GEMM.
// Sizes: B=32 S=64 V=32000 E=128 H=512 L=2 LAT=64.
// r15: single persistent kernel. embed+encoder (WGs 48..79 -> batch g, E
//      flags) and Wih0 cvt (WGs 80..111, C flags) folded into the GEMM
//      role's idle head; xW0 producers gate on E+C; L0/L1 gate on E before
//      reading state. All exchange via bypass stores + flag gating (proven
//      pattern). r14: 347us = 330 fused + 17 serial pre-work.

typedef __attribute__((ext_vector_type(8))) short bf16x8_t;
typedef __attribute__((ext_vector_type(8))) unsigned short u16x8_t;
typedef __attribute__((ext_vector_type(4))) float f32x4_t;
typedef __attribute__((ext_vector_type(8))) _Float16 f16x8_t;
typedef __attribute__((ext_vector_type(4))) unsigned int u32x4_t;

#define AS_AGENT __HIP_MEMORY_SCOPE_AGENT

static __device__ __forceinline__ unsigned short f2bf(float f) {
    unsigned int u = __float_as_uint(f);
    u += 0x7fffu + ((u >> 16) & 1u);
    return (unsigned short)(u >> 16);
}
static __device__ __forceinline__ unsigned short bfround(unsigned int u) {
    u += 0x7fffu + ((u >> 16) & 1u);
    return (unsigned short)(u >> 16);
}
static __device__ __forceinline__ unsigned short f2h(float f) {
    _Float16 h = (_Float16)f;
    return __builtin_bit_cast(unsigned short, h);
}
static __device__ __forceinline__ float sigmoidf_(float x) {
    return 1.f / (1.f + __expf(-x));
}

// flag layout (ints): WG flags wg<<5 (0..1504); panel 2048+n*16; tile
// 8192+g*16; E (encoder) 12288+b*16; C (Wih0 cvt) 13312+j*16.
#define NWG_L0 16
#define NWG_TOT 48
#define NWG_ALL 256
#define NWG_GEMM 208
#define OCH 32832   // out1x chunk stride in u32 (=65664 ushorts = 131328 B)

__global__ __launch_bounds__(512) void gru_fused_kernel(
    const int* __restrict__ tok, const float* __restrict__ table,
    const float* __restrict__ Wm, const float* __restrict__ bm,
    const float* __restrict__ Wv, const float* __restrict__ bv,
    const float* __restrict__ noise,
    const float* __restrict__ Wl2r, const float* __restrict__ bl2r,
    const float* __restrict__ lW1, const float* __restrict__ lb1,
    const float* __restrict__ lW2, const float* __restrict__ lb2,
    const float* __restrict__ lW3, const float* __restrict__ lb3,
    const float* __restrict__ sW1, const float* __restrict__ sb1,
    const float* __restrict__ sW2, const float* __restrict__ sb2,
    const float* __restrict__ sW3, const float* __restrict__ sb3,
    const float* __restrict__ Wih0f, const float* __restrict__ bih0,
    const float* __restrict__ Whh0, const float* __restrict__ bhh0,
    const float* __restrict__ Whh1, const float* __restrict__ Wih1,
    const float* __restrict__ bih1, const float* __restrict__ bhh1,
    const int* __restrict__ lengths,
    const float* __restrict__ Woutf, const float* __restrict__ bout,
    float* __restrict__ outp,          // (B,S,V) f32
    float* __restrict__ aux,           // o_mean base (then std/z/logp/sas)
    unsigned short* __restrict__ embb, // 2048x128 bf16 (in-kernel)
    unsigned short* __restrict__ Wih0b,// 1536x128 bf16 (in-kernel)
    float* __restrict__ state,         // 2x32x512 (in-kernel)
    float* __restrict__ xW0,           // 2048x1536 f32 (in-kernel)
    unsigned short* __restrict__ h0x,  // 2 x 32 x 512 f16
    unsigned short* __restrict__ h1x,  // 2 x 32 x 512 f16
    unsigned short* __restrict__ o0x,  // 4 x 32 x 512 f16
    unsigned short* __restrict__ out1x,// 16 chunks x (128x512 + pad) bf16 t-major
    unsigned short* __restrict__ Woutb,// 32000 x 512 bf16 (in-kernel)
    int* __restrict__ flags)           // 16384 ints (zeroed)
{
    __shared__ __align__(16) char smem[157184];
    const int tid = threadIdx.x;
    const int wg = blockIdx.x;
    const int lane = tid & 63;
    const int wave = tid >> 6;                // 0..7
    unsigned int* __restrict__ h0x32 = (unsigned int*)h0x;
    unsigned int* __restrict__ h1x32 = (unsigned int*)h1x;
    unsigned int* __restrict__ o0x32 = (unsigned int*)o0x;
    unsigned int* __restrict__ o1x32 = (unsigned int*)out1x;

    // defensive agent-acquire: drop any stale/poison L2 lines at kernel start
    (void)__hip_atomic_load(&flags[0], __ATOMIC_ACQUIRE, AS_AGENT);

    if (wg >= NWG_TOT) {
        // ================= GEMM role =================
        unsigned short* lA = (unsigned short*)smem;            // 128 x 64 bf16
        unsigned short* lB = (unsigned short*)(smem + 16384);  // 128 x 64 bf16
        const int g = wg - NWG_TOT;            // 0..207
        const int wm = wave >> 2;              // 0..1 (64-row m half)
        const int wn = wave & 3;               // 0..3 (32-col n quad)

        // ---- (0a) embed + encoder for batch b = g (WGs g<32) ----
        if (g < 32) {
            const int b = g;
            float* v_  = (float*)smem;          // 128
            float* mn  = v_ + 128;              // 64
            float* sd  = mn + 64;               // 64
            float* zz  = sd + 64;               // 2x64
            float* hh1 = zz + 128;              // 200
            float* hh2 = hh1 + 200;             // 100
            float* o_mean = aux, *o_std = aux + 2048, *o_z = aux + 4096;
            float* o_logp = aux + 8192, *o_sas = aux + 8224;
            if (tid < 128) {
                const int e = tid;
                float acc = 0.f;
                for (int s = 0; s < 64; ++s) {
                    int id = tok[b * 64 + s];
                    float v = table[(size_t)id * 128 + e];
                    __hip_atomic_store(&embb[(size_t)(b * 64 + s) * 128 + e],
                                       f2bf(v), __ATOMIC_RELAXED, AS_AGENT);
                    if (id > 2) acc += v;
                }
                v_[e] = acc;
            }
            __syncthreads();
            if (tid < 128) {
                int j = tid & 63;
                bool isv = tid >= 64;
                const float* W = (isv ? Wv : Wm) + j * 128;
                float a = isv ? bv[j] : bm[j];
#pragma unroll 4
                for (int k = 0; k < 128; ++k) a = fmaf(v_[k], W[k], a);
                if (!isv) { mn[j] = a; o_mean[b * 64 + j] = a; }
                else      { float s = __expf(0.5f * a); sd[j] = s; o_std[b * 64 + j] = s; }
            }
            __syncthreads();
            if (tid < 128) {
                int l = tid >> 6, j = tid & 63;
                float zv = fmaf(noise[(l * 32 + b) * 64 + j], sd[j], mn[j]);
                zz[l * 64 + j] = zv;
                o_z[(l * 32 + b) * 64 + j] = zv;
            }
            __syncthreads();
#pragma unroll
            for (int p = 0; p < 2; ++p) {      // 1024 state rows over 512 thr
                int tt = p * 512 + tid;
                int l = tt >> 9, hd = tt & 511;
                const float* W = Wl2r + hd * 64;
                float a = bl2r[hd];
#pragma unroll 4
                for (int k = 0; k < 64; ++k) a = fmaf(zz[l * 64 + k], W[k], a);
                __hip_atomic_store(&state[(size_t)(l * 32 + b) * 512 + hd],
                                   a, __ATOMIC_RELAXED, AS_AGENT);
            }
            if (tid < 200) {
                const float* W = lW1 + tid * 64;
                float a = lb1[tid];
                for (int k = 0; k < 64; ++k) a = fmaf(mn[k], W[k], a);
                hh1[tid] = fmaxf(a, 0.f);
            }
            __syncthreads();
            if (tid < 100) {
                const float* W = lW2 + tid * 200;
                float a = lb2[tid];
                for (int k = 0; k < 200; ++k) a = fmaf(hh1[k], W[k], a);
                hh2[tid] = fmaxf(a, 0.f);
            }
            __syncthreads();
            if (tid == 0) {
                float a = lb3[0];
                for (int k = 0; k < 100; ++k) a = fmaf(hh2[k], lW3[k], a);
                o_logp[b] = a;
            }
            __syncthreads();
            if (tid < 200) {
                const float* W = sW1 + tid * 64;
                float a = sb1[tid];
                for (int k = 0; k < 64; ++k) a = fmaf(mn[k], W[k], a);
                hh1[tid] = fmaxf(a, 0.f);
            }
            __syncthreads();
            if (tid < 100) {
                const float* W = sW2 + tid * 200;
                float a = sb2[tid];
                for (int k = 0; k < 200; ++k) a = fmaf(hh1[k], W[k], a);
                hh2[tid] = fmaxf(a, 0.f);
            }
            __syncthreads();
            if (tid == 0) {
                float a = sb3[0];
                for (int k = 0; k < 100; ++k) a = fmaf(hh2[k], sW3[k], a);
                o_sas[b] = a;
            }
            asm volatile("s_waitcnt vmcnt(0)" ::: "memory");
            __syncthreads();
            if (tid == 0)
                __hip_atomic_store(&flags[12288 + b * 16], 1, __ATOMIC_RELAXED, AS_AGENT);
        }
        // ---- (0b) Wih0 f32->bf16 cvt (WGs 32..63, 1536 float4 each) ----
        if (g >= 32 && g < 64) {
            const int j = g - 32;
            for (int i = j * 1536 + tid; i < (j + 1) * 1536; i += 512) {
                float4 v = reinterpret_cast<const float4*>(Wih0f)[i];
                unsigned int lo = (unsigned int)f2bf(v.x) | ((unsigned int)f2bf(v.y) << 16);
                unsigned int hi = (unsigned int)f2bf(v.z) | ((unsigned int)f2bf(v.w) << 16);
                unsigned long long w = (unsigned long long)lo | ((unsigned long long)hi << 32);
                __hip_atomic_store((unsigned long long*)Wih0b + i, w, __ATOMIC_RELAXED, AS_AGENT);
            }
            asm volatile("s_waitcnt vmcnt(0)" ::: "memory");
            __syncthreads();
            if (tid == 0)
                __hip_atomic_store(&flags[13312 + j * 16], 1, __ATOMIC_RELAXED, AS_AGENT);
        }

        // ---- (1) xW0 producer: tile (pm, pn), gated on E + C flags ----
        if (g < 192) {
            if (wave == 0) {
                for (;;) {
                    int v = 1;
                    if (lane < 32) {
                        int e = __hip_atomic_load(&flags[12288 + lane * 16],
                                                  __ATOMIC_RELAXED, AS_AGENT);
                        int c = __hip_atomic_load(&flags[13312 + lane * 16],
                                                  __ATOMIC_RELAXED, AS_AGENT);
                        v = e < c ? e : c;
                    }
                    if (__all(v >= 1)) break;
                    __builtin_amdgcn_s_sleep(2);
                }
            }
            __syncthreads();
            const int pm = g / 12, pn = g % 12;
            f32x4_t pacc[4][2];
#pragma unroll
            for (int i = 0; i < 4; ++i)
#pragma unroll
                for (int j = 0; j < 2; ++j) pacc[i][j] = (f32x4_t){0.f, 0.f, 0.f, 0.f};
            for (int kt = 0; kt < 128; kt += 64) {
#pragma unroll
                for (int p = 0; p < 2; ++p) {
                    int gi = p * 512 + tid;
                    int row = gi >> 3, c8 = gi & 7;
                    int dst = row * 64 + ((c8 ^ (row & 7)) << 3);
                    *(u32x4_t*)&lA[dst] = *(const u32x4_t*)(embb +
                        (size_t)(pm * 128 + row) * 128 + kt + (c8 << 3));
                    *(u32x4_t*)&lB[dst] = *(const u32x4_t*)(Wih0b +
                        (size_t)(pn * 128 + row) * 128 + kt + (c8 << 3));
                }
                __syncthreads();
#pragma unroll
                for (int kc = 0; kc < 2; ++kc) {
                    int c8 = kc * 4 + (lane >> 4);
                    bf16x8_t af[4], bfr[2];
#pragma unroll
                    for (int i = 0; i < 4; ++i) {
                        int ra = wm * 64 + i * 16 + (lane & 15);
                        af[i] = *(const bf16x8_t*)&lA[ra * 64 + ((c8 ^ (ra & 7)) << 3)];
                    }
#pragma unroll
                    for (int j = 0; j < 2; ++j) {
                        int rb = wn * 32 + j * 16 + (lane & 15);
                        bfr[j] = *(const bf16x8_t*)&lB[rb * 64 + ((c8 ^ (rb & 7)) << 3)];
                    }
#pragma unroll
                    for (int i = 0; i < 4; ++i)
#pragma unroll
                        for (int j = 0; j < 2; ++j)
                            pacc[i][j] = __builtin_amdgcn_mfma_f32_16x16x32_bf16(
                                af[i], bfr[j], pacc[i][j], 0, 0, 0);
                }
                __syncthreads();
            }
            const int lm = (lane >> 4) * 4, ln = lane & 15;
#pragma unroll
            for (int i = 0; i < 4; ++i) {
#pragma unroll
                for (int j = 0; j < 2; ++j) {
                    int gn = pn * 128 + wn * 32 + j * 16 + ln;
                    float bb_ = bih0[gn];
#pragma unroll
                    for (int r = 0; r < 4; ++r) {
                        int gm = pm * 128 + wm * 64 + i * 16 + lm + r;
                        __hip_atomic_store(&xW0[(size_t)gm * 1536 + gn],
                                           pacc[i][j][r] + bb_, __ATOMIC_RELAXED, AS_AGENT);
                    }
                }
            }
            asm volatile("s_waitcnt vmcnt(0)" ::: "memory");
            __syncthreads();
            if (tid == 0)
                __hip_atomic_store(&flags[8192 + g * 16], 1, __ATOMIC_RELAXED, AS_AGENT);
        }

        // ---- (2) JIT cvt: WG g converts its own panels (n = g, g+208<250) ----
        for (int pn = g; pn < 250; pn += NWG_GEMM) {
            const u32x4_t* src = (const u32x4_t*)Woutf + (size_t)pn * 16384;
            unsigned long long* dst = (unsigned long long*)Woutb + (size_t)pn * 16384;
            for (int i = tid; i < 16384; i += 512) {
                u32x4_t q = __builtin_nontemporal_load(src + i);   // read-once: nt
                unsigned int lo = (unsigned int)bfround(q[0]) | ((unsigned int)bfround(q[1]) << 16);
                unsigned int hi = (unsigned int)bfround(q[2]) | ((unsigned int)bfround(q[3]) << 16);
                unsigned long long w = (unsigned long long)lo | ((unsigned long long)hi << 32);
                __hip_atomic_store(dst + i, w, __ATOMIC_RELAXED, AS_AGENT);  // bypass
            }
            asm volatile("s_waitcnt vmcnt(0)" ::: "memory");
            __syncthreads();
            if (tid == 0)
                __hip_atomic_store(&flags[2048 + pn * 16], 1, __ATOMIC_RELAXED, AS_AGENT);
        }

        // ---- (3) main loop: single-m tiles (r12 structure) ----
        int mPrev = -1;
        for (int T = g; T < 4000; T += NWG_GEMM) {
            const int m = T / 250, n = T % 250;
            if (m != mPrev) {
                if (wave == 0) {
                    const int tgt = 4 * m + 6;   // L1 finished t1 <= 4m+3
                    for (;;) {
                        int v = 0x40000000;
                        if (lane < 32)
                            v = __hip_atomic_load(&flags[(NWG_L0 + lane) << 5],
                                                  __ATOMIC_RELAXED, AS_AGENT);
                        if (__all(v >= tgt)) break;
                        __builtin_amdgcn_s_sleep(8);
                    }
                }
                mPrev = m;
            }
            if (wave == 0) {
                while (__hip_atomic_load(&flags[2048 + n * 16], __ATOMIC_RELAXED, AS_AGENT) < 1)
                    __builtin_amdgcn_s_sleep(8);
            }
            __syncthreads();

            f32x4_t acc[4][2];
#pragma unroll
            for (int i = 0; i < 4; ++i)
#pragma unroll
                for (int j = 0; j < 2; ++j) acc[i][j] = (f32x4_t){0.f, 0.f, 0.f, 0.f};

            for (int kt = 0; kt < 512; kt += 64) {
#pragma unroll
                for (int p = 0; p < 2; ++p) {
                    int gi = p * 512 + tid;
                    int row = gi >> 3, c8 = gi & 7;
                    int dst = row * 64 + ((c8 ^ (row & 7)) << 3);
                    u32x4_t qa = *(const u32x4_t*)(out1x + (size_t)m * 65664 +
                                                   row * 512 + kt + (c8 << 3));
                    u32x4_t qb = *(const u32x4_t*)(Woutb + ((size_t)(n * 128 + row)) * 512 +
                                                   kt + (c8 << 3));
                    *(u32x4_t*)&lA[dst] = qa;
                    *(u32x4_t*)&lB[dst] = qb;
                }
                __syncthreads();
#pragma unroll
                for (int kc = 0; kc < 2; ++kc) {
                    bf16x8_t af[4], bfr[2];
                    int c8 = kc * 4 + (lane >> 4);
#pragma unroll
                    for (int i = 0; i < 4; ++i) {
                        int ra = wm * 64 + i * 16 + (lane & 15);
                        af[i] = *(const bf16x8_t*)&lA[ra * 64 + ((c8 ^ (ra & 7)) << 3)];
                    }
#pragma unroll
                    for (int j = 0; j < 2; ++j) {
                        int rb = wn * 32 + j * 16 + (lane & 15);
                        bfr[j] = *(const bf16x8_t*)&lB[rb * 64 + ((c8 ^ (rb & 7)) << 3)];
                    }
#pragma unroll
                    for (int i = 0; i < 4; ++i)
#pragma unroll
                        for (int j = 0; j < 2; ++j)
                            acc[i][j] = __builtin_amdgcn_mfma_f32_16x16x32_bf16(
                                af[i], bfr[j], acc[i][j], 0, 0, 0);
                }
                __syncthreads();
            }
            const int lm = (lane >> 4) * 4, ln = lane & 15;
#pragma unroll
            for (int i = 0; i < 4; ++i) {
                int rl0 = wm * 64 + i * 16 + lm;
#pragma unroll
                for (int j = 0; j < 2; ++j) {
                    int gn = n * 128 + wn * 32 + j * 16 + ln;
                    float bb = bout[gn];
#pragma unroll
                    for (int r = 0; r < 4; ++r) {
                        int rl = rl0 + r;
                        int t = 4 * m + (rl >> 5), b = rl & 31;
                        __builtin_nontemporal_store(acc[i][j][r] + bb,
                            &outp[(size_t)(b * 64 + t) * 32000 + gn]);
                    }
                }
            }
        }
        return;
    }

    // ================= scan roles =================
    unsigned short* Wl = (unsigned short*)smem;             // 96 KB f16 B-fragments
    u32x4_t* hstage4 = (u32x4_t*)(smem + 98304);            // 32 KB gather stage
    float* csm = (float*)(smem + 131072);                   // [2][3][32][34]
#define CSM(p, gt, b, c) csm[((((p)*3 + (gt)) * 32 + (b)) * 34) + (c)]
    const int gate = wave >> 1;         // 0=r 1=z 2=n (waves 0..5)
    const int mt = wave & 1;            // M-tile (batches 0-15 / 16-31)

    if (wg < NWG_L0) {
        // ================= L0 role: d-slice 32 =================
        const int d0 = wg * 32;
        for (int idx = tid; idx < 6144; idx += 512) {
            int ln = idx & 63, kk = (idx >> 6) & 15, nt = (idx >> 10) & 1, g_ = idx >> 11;
            int grow = g_ * 512 + d0 + nt * 16 + (ln & 15);
            int k = kk * 32 + ((ln >> 4) << 3);
            const float* src = Whh0 + (size_t)grow * 512 + k;
            f16x8_t v;
#pragma unroll
            for (int j = 0; j < 8; ++j) v[j] = (_Float16)src[j];
            *(f16x8_t*)&Wl[idx << 3] = v;
        }
        // gate on encoder completion (state readable)
        if (wave == 0) {
            for (;;) {
                int v = 1;
                if (lane < 32) v = __hip_atomic_load(&flags[12288 + lane * 16],
                                                     __ATOMIC_RELAXED, AS_AGENT);
                if (__all(v >= 1)) break;
                __builtin_amdgcn_s_sleep(2);
            }
        }
        __syncthreads();
        const int ub = tid >> 4, dpl = (tid & 15) * 2, ud = d0 + dpl;
        float h_lo = state[(size_t)ub * 512 + ud];
        float h_hi = state[(size_t)ub * 512 + ud + 1];
        const float br_lo = bhh0[ud],        br_hi = bhh0[ud + 1];
        const float bz_lo = bhh0[512 + ud],  bz_hi = bhh0[512 + ud + 1];
        const float bn_lo = bhh0[1024 + ud], bn_hi = bhh0[1024 + ud + 1];
        const int lenb = lengths[ub];
        {   // init publish h0 -> h0x[0]
            unsigned int hw = (unsigned int)f2h(h_lo) | ((unsigned int)f2h(h_hi) << 16);
            __hip_atomic_store(&h0x32[ub * 256 + (ud >> 1)], hw, __ATOMIC_RELAXED, AS_AGENT);
        }
        asm volatile("s_waitcnt vmcnt(0)" ::: "memory");
        __syncthreads();
        if (tid == 0) __hip_atomic_store(&flags[wg << 5], 1, __ATOMIC_RELAXED, AS_AGENT);

        // one-time pre-poll: all 192 xW0 tiles published
        if (wave == 0) {
            for (;;) {
                int mnv = 1;
#pragma unroll
                for (int bb = 0; bb < 3; ++bb) {
                    int idx = bb * 64 + lane;
                    if (idx < 192) {
                        int v = __hip_atomic_load(&flags[8192 + idx * 16],
                                                  __ATOMIC_RELAXED, AS_AGENT);
                        mnv = v < mnv ? v : mnv;
                    }
                }
                if (__all(mnv >= 1)) break;
                __builtin_amdgcn_s_sleep(2);
            }
        }
        __syncthreads();

        // xW0 prefetch for t=0 (safe: producers drained before tile flags)
        const float* xrow = xW0 + (size_t)(ub * 64) * 1536 + ud;
        float2 px_r = *(const float2*)(xrow);
        float2 px_z = *(const float2*)(xrow + 512);
        float2 px_n = *(const float2*)(xrow + 1024);

        for (int r = 0; r < 64; ++r) {
            // decoupled poll: own group at r+1; L1 only at r-2 (o0x slot WAR)
            if (wave == 0) {
                for (;;) {
                    int v = 0x40000000;
                    int tgt = (lane < NWG_L0) ? (r + 1) : (r - 2);
                    if (lane < NWG_TOT)
                        v = __hip_atomic_load(&flags[lane << 5], __ATOMIC_RELAXED, AS_AGENT);
                    else
                        tgt = 0;
                    if (__all(v >= tgt)) break;
                    __builtin_amdgcn_s_sleep(1);
                }
            }
            __syncthreads();
            // gather h0x[r&1] -> stage
            {
                const char* srcb = (const char*)h0x + ((r & 1) << 15);
                u32x4_t q0, q1, q2, q3;
                asm volatile("global_load_dwordx4 %0, %1, off sc0 sc1"
                             : "=v"(q0) : "v"(srcb + ((size_t)tid << 4)) : "memory");
                asm volatile("global_load_dwordx4 %0, %1, off sc0 sc1"
                             : "=v"(q1) : "v"(srcb + ((size_t)(512 + tid) << 4)) : "memory");
                asm volatile("global_load_dwordx4 %0, %1, off sc0 sc1"
                             : "=v"(q2) : "v"(srcb + ((size_t)(1024 + tid) << 4)) : "memory");
                asm volatile("global_load_dwordx4 %0, %1, off sc0 sc1"
                             : "=v"(q3) : "v"(srcb + ((size_t)(1536 + tid) << 4)) : "memory");
                asm volatile("s_waitcnt vmcnt(0)" ::: "memory");
                int g0 = tid, g1 = 512 + tid, g2 = 1024 + tid, g3 = 1536 + tid;
                hstage4[g0 ^ ((g0 >> 6) & 7)] = q0;
                hstage4[g1 ^ ((g1 >> 6) & 7)] = q1;
                hstage4[g2 ^ ((g2 >> 6) & 7)] = q2;
                hstage4[g3 ^ ((g3 >> 6) & 7)] = q3;
            }
            __syncthreads();
            if (wave < 6) {
                const int brow = mt * 16 + (lane & 15);
                const int ko = lane >> 4;
                f32x4_t acc0 = (f32x4_t){0.f, 0.f, 0.f, 0.f};
                f32x4_t acc1 = (f32x4_t){0.f, 0.f, 0.f, 0.f};
#pragma unroll
                for (int kk = 0; kk < 16; ++kk) {
                    int gg = brow * 64 + kk * 4 + ko;
                    f16x8_t af = __builtin_bit_cast(f16x8_t, hstage4[gg ^ (brow & 7)]);
                    f16x8_t bf0 = *(const f16x8_t*)&Wl[(((gate * 2 + 0) * 16 + kk) * 64 + lane) << 3];
                    f16x8_t bf1 = *(const f16x8_t*)&Wl[(((gate * 2 + 1) * 16 + kk) * 64 + lane) << 3];
                    acc0 = __builtin_amdgcn_mfma_f32_16x16x32_f16(af, bf0, acc0, 0, 0, 0);
                    acc1 = __builtin_amdgcn_mfma_f32_16x16x32_f16(af, bf1, acc1, 0, 0, 0);
                }
                const int crow = mt * 16 + ((lane >> 4) << 2), ccol = lane & 15;
#pragma unroll
                for (int rr = 0; rr < 4; ++rr) {
                    CSM(0, gate, crow + rr, ccol) = acc0[rr];
                    CSM(0, gate, crow + rr, 16 + ccol) = acc1[rr];
                }
            }
            __syncthreads();
            // gate update
            unsigned int ow = 0u;
            if (r < lenb) {
                float hr_lo = CSM(0, 0, ub, dpl), hr_hi = CSM(0, 0, ub, dpl + 1);
                float hz_lo = CSM(0, 1, ub, dpl), hz_hi = CSM(0, 1, ub, dpl + 1);
                float hn_lo = CSM(0, 2, ub, dpl), hn_hi = CSM(0, 2, ub, dpl + 1);
                float r0 = sigmoidf_(px_r.x + hr_lo + br_lo);
                float r1 = sigmoidf_(px_r.y + hr_hi + br_hi);
                float u0 = sigmoidf_(px_z.x + hz_lo + bz_lo);
                float u1 = sigmoidf_(px_z.y + hz_hi + bz_hi);
                float n0 = tanhf(px_n.x + r0 * (hn_lo + bn_lo));
                float n1 = tanhf(px_n.y + r1 * (hn_hi + bn_hi));
                h_lo = (1.f - u0) * n0 + u0 * h_lo;
                h_hi = (1.f - u1) * n1 + u1 * h_hi;
                ow = (unsigned int)f2h(h_lo) | ((unsigned int)f2h(h_hi) << 16);
            }
            // publish h0_{t+1} and out0[t] (o0x slot r&3, 4-deep)
            {
                unsigned int hw = (unsigned int)f2h(h_lo) | ((unsigned int)f2h(h_hi) << 16);
                __hip_atomic_store(&h0x32[((r + 1) & 1) * 8192 + ub * 256 + (ud >> 1)],
                                   hw, __ATOMIC_RELAXED, AS_AGENT);
                __hip_atomic_store(&o0x32[(r & 3) * 8192 + ub * 256 + (ud >> 1)],
                                   ow, __ATOMIC_RELAXED, AS_AGENT);
            }
            asm volatile("s_waitcnt vmcnt(0)" ::: "memory");
            __syncthreads();
            if (tid == 0) __hip_atomic_store(&flags[wg << 5], r + 2, __ATOMIC_RELAXED, AS_AGENT);
            // off-chain: xW0 prefetch for t=r+1
            {
                int tn = r + 1 < 64 ? r + 1 : 63;
                const float* xp = xW0 + (size_t)(ub * 64 + tn) * 1536 + ud;
                px_r = *(const float2*)(xp);
                px_z = *(const float2*)(xp + 512);
                px_n = *(const float2*)(xp + 1024);
            }
        }
    } else {
        // ================= L1 role: d-slice 16, K=1024 =================
        const int lid = wg - NWG_L0;
        const int d0 = lid * 16;
        for (int idx = tid; idx < 6144; idx += 512) {
            int ln = idx & 63, kk = (idx >> 6) & 31, g_ = idx >> 11;
            int grow = g_ * 512 + d0 + (ln & 15);
            int k = (kk & 15) * 32 + ((ln >> 4) << 3);
            const float* src = (kk < 16 ? Whh1 : Wih1) + (size_t)grow * 512 + k;
            f16x8_t v;
#pragma unroll
            for (int j = 0; j < 8; ++j) v[j] = (_Float16)src[j];
            *(f16x8_t*)&Wl[idx << 3] = v;
        }
        // gate on encoder completion (state readable)
        if (wave == 0) {
            for (;;) {
                int v = 1;
                if (lane < 32) v = __hip_atomic_load(&flags[12288 + lane * 16],
                                                     __ATOMIC_RELAXED, AS_AGENT);
                if (__all(v >= 1)) break;
                __builtin_amdgcn_s_sleep(2);
            }
        }
        __syncthreads();
        const bool upd = (tid < 256);
        const int ub = tid >> 3, dpl = (tid & 7) * 2, ud = d0 + dpl;
        float h_lo = 0.f, h_hi = 0.f;
        float br_lo = 0.f, br_hi = 0.f, bz_lo = 0.f, bz_hi = 0.f;
        float bxn_lo = 0.f, bxn_hi = 0.f, bhn_lo = 0.f, bhn_hi = 0.f;
        int lenb = 0;
        if (upd) {
            h_lo = state[16384 + (size_t)ub * 512 + ud];
            h_hi = state[16384 + (size_t)ub * 512 + ud + 1];
            br_lo = bih1[ud] + bhh1[ud];
            br_hi = bih1[ud + 1] + bhh1[ud + 1];
            bz_lo = bih1[512 + ud] + bhh1[512 + ud];
            bz_hi = bih1[512 + ud + 1] + bhh1[512 + ud + 1];
            bxn_lo = bih1[1024 + ud];   bxn_hi = bih1[1024 + ud + 1];
            bhn_lo = bhh1[1024 + ud];   bhn_hi = bhh1[1024 + ud + 1];
            lenb = lengths[ub];
            // init publish h1 -> h1x[1] (round 1 reads parity 1)
            unsigned int hw = (unsigned int)f2h(h_lo) | ((unsigned int)f2h(h_hi) << 16);
            __hip_atomic_store(&h1x32[8192 + ub * 256 + (ud >> 1)], hw, __ATOMIC_RELAXED, AS_AGENT);
        }
        asm volatile("s_waitcnt vmcnt(0)" ::: "memory");
        __syncthreads();
        if (tid == 0) __hip_atomic_store(&flags[wg << 5], 2, __ATOMIC_RELAXED, AS_AGENT);

        for (int r = 1; r <= 64; ++r) {
            const int t1 = r - 1;
            if (wave == 0) {
                const int tgt = r + 1;
                for (;;) {
                    int v = 0x40000000;
                    if (lane < NWG_TOT)
                        v = __hip_atomic_load(&flags[lane << 5], __ATOMIC_RELAXED, AS_AGENT);
                    if (__all(v >= tgt)) break;
                    __builtin_amdgcn_s_sleep(1);
                }
            }
            __syncthreads();
            // gather: h1 first (4 loads), then out0 slot t1&3 (4 loads)
            u32x4_t a0, a1, a2, a3, b0, b1, b2, b3;
            {
                const char* sh = (const char*)h1x + ((r & 1) << 15);
                const char* so = (const char*)o0x + ((t1 & 3) << 15);
                asm volatile("global_load_dwordx4 %0, %1, off sc0 sc1"
                             : "=v"(a0) : "v"(sh + ((size_t)tid << 4)) : "memory");
                asm volatile("global_load_dwordx4 %0, %1, off sc0 sc1"
                             : "=v"(a1) : "v"(sh + ((size_t)(512 + tid) << 4)) : "memory");
                asm volatile("global_load_dwordx4 %0, %1, off sc0 sc1"
                             : "=v"(a2) : "v"(sh + ((size_t)(1024 + tid) << 4)) : "memory");
                asm volatile("global_load_dwordx4 %0, %1, off sc0 sc1"
                             : "=v"(a3) : "v"(sh + ((size_t)(1536 + tid) << 4)) : "memory");
                asm volatile("global_load_dwordx4 %0, %1, off sc0 sc1"
                             : "=v"(b0) : "v"(so + ((size_t)tid << 4)) : "memory");
                asm volatile("global_load_dwordx4 %0, %1, off sc0 sc1"
                             : "=v"(b1) : "v"(so + ((size_t)(512 + tid) << 4)) : "memory");
                asm volatile("global_load_dwordx4 %0, %1, off sc0 sc1"
                             : "=v"(b2) : "v"(so + ((size_t)(1024 + tid) << 4)) : "memory");
                asm volatile("global_load_dwordx4 %0, %1, off sc0 sc1"
                             : "=v"(b3) : "v"(so + ((size_t)(1536 + tid) << 4)) : "memory");
                asm volatile("s_waitcnt vmcnt(4)" ::: "memory");  // h1 done
                int g0 = tid, g1 = 512 + tid, g2 = 1024 + tid, g3 = 1536 + tid;
                hstage4[g0 ^ ((g0 >> 6) & 7)] = a0;
                hstage4[g1 ^ ((g1 >> 6) & 7)] = a1;
                hstage4[g2 ^ ((g2 >> 6) & 7)] = a2;
                hstage4[g3 ^ ((g3 >> 6) & 7)] = a3;
            }
            __syncthreads();
            // pass 0: acc_h = h1 @ Whh1^T (one 16x16 tile per wave)
            f32x4_t acc_h = (f32x4_t){0.f, 0.f, 0.f, 0.f};
            const int brow = mt * 16 + (lane & 15);
            const int ko = lane >> 4;
            if (wave < 6) {
#pragma unroll
                for (int kk = 0; kk < 16; ++kk) {
                    int gg = brow * 64 + kk * 4 + ko;
                    f16x8_t af = __builtin_bit_cast(f16x8_t, hstage4[gg ^ (brow & 7)]);
                    f16x8_t bf = *(const f16x8_t*)&Wl[(((gate * 32 + kk) * 64 + lane)) << 3];
                    acc_h = __builtin_amdgcn_mfma_f32_16x16x32_f16(af, bf, acc_h, 0, 0, 0);
                }
            }
            __syncthreads();  // all reads of h1 stage done
            {
                asm volatile("s_waitcnt vmcnt(0)" ::: "memory");  // out0 done
                int g0 = tid, g1 = 512 + tid, g2 = 1024 + tid, g3 = 1536 + tid;
                hstage4[g0 ^ ((g0 >> 6) & 7)] = b0;
                hstage4[g1 ^ ((g1 >> 6) & 7)] = b1;
                hstage4[g2 ^ ((g2 >> 6) & 7)] = b2;
                hstage4[g3 ^ ((g3 >> 6) & 7)] = b3;
            }
            __syncthreads();
            // pass 1: acc_x = out0 @ Wih1^T
            if (wave < 6) {
                f32x4_t acc_x = (f32x4_t){0.f, 0.f, 0.f, 0.f};
#pragma unroll
                for (int kk = 0; kk < 16; ++kk) {
                    int gg = brow * 64 + kk * 4 + ko;
                    f16x8_t af = __builtin_bit_cast(f16x8_t, hstage4[gg ^ (brow & 7)]);
                    f16x8_t bf = *(const f16x8_t*)&Wl[(((gate * 32 + 16 + kk) * 64 + lane)) << 3];
                    acc_x = __builtin_amdgcn_mfma_f32_16x16x32_f16(af, bf, acc_x, 0, 0, 0);
                }
                const int crow = mt * 16 + ((lane >> 4) << 2), ccol = lane & 15;
#pragma unroll
                for (int rr = 0; rr < 4; ++rr) {
                    CSM(0, gate, crow + rr, ccol) = acc_h[rr];
                    CSM(1, gate, crow + rr, ccol) = acc_x[rr];
                }
            }
            __syncthreads();
            // gate update (n-gate: x-part and h-part kept separate)
            unsigned int ow = 0u;
            if (upd) {
                if (t1 < lenb) {
                    float hr_lo = CSM(0, 0, ub, dpl), hr_hi = CSM(0, 0, ub, dpl + 1);
                    float hz_lo = CSM(0, 1, ub, dpl), hz_hi = CSM(0, 1, ub, dpl + 1);
                    float hn_lo = CSM(0, 2, ub, dpl), hn_hi = CSM(0, 2, ub, dpl + 1);
                    float xr_lo = CSM(1, 0, ub, dpl), xr_hi = CSM(1, 0, ub, dpl + 1);
                    float xz_lo = CSM(1, 1, ub, dpl), xz_hi = CSM(1, 1, ub, dpl + 1);
                    float xn_lo = CSM(1, 2, ub, dpl), xn_hi = CSM(1, 2, ub, dpl + 1);
                    float r0 = sigmoidf_(xr_lo + hr_lo + br_lo);
                    float r1 = sigmoidf_(xr_hi + hr_hi + br_hi);
                    float u0 = sigmoidf_(xz_lo + hz_lo + bz_lo);
                    float u1 = sigmoidf_(xz_hi + hz_hi + bz_hi);
                    float n0 = tanhf(xn_lo + bxn_lo + r0 * (hn_lo + bhn_lo));
                    float n1 = tanhf(xn_hi + bxn_hi + r1 * (hn_hi + bhn_hi));
                    h_lo = (1.f - u0) * n0 + u0 * h_lo;
                    h_hi = (1.f - u1) * n1 + u1 * h_hi;
                    ow = (unsigned int)f2bf(h_lo) | ((unsigned int)f2bf(h_hi) << 16);
                }
                if (r < 64) {
                    unsigned int hw = (unsigned int)f2h(h_lo) | ((unsigned int)f2h(h_hi) << 16);
                    __hip_atomic_store(&h1x32[((r + 1) & 1) * 8192 + ub * 256 + (ud >> 1)],
                                       hw, __ATOMIC_RELAXED, AS_AGENT);
                }
                // out1 publish: padded t-major bf16 chunks, bypass, pre-drain
                __hip_atomic_store(&o1x32[(size_t)(t1 >> 2) * OCH +
                                          ((t1 & 3) * 32 + ub) * 256 + (ud >> 1)],
                                   ow, __ATOMIC_RELAXED, AS_AGENT);
            }
            asm volatile("s_waitcnt vmcnt(0)" ::: "memory");
            __syncthreads();
            if (tid == 0)
                __hip_atomic_store(&flags[wg << 5], r + 2, __ATOMIC_RELAXED, AS_AGENT);
        }
    }
#undef CSM
}

extern "C" void kernel_launch(void* const* d_in, const int* in_sizes, int n_in,
                              void* d_out, int out_size, void* d_ws, size_t ws_size,
                              hipStream_t stream) {
    const int*   tok    = (const int*)d_in[0];
    const int*   lens   = (const int*)d_in[1];
    const float* noise  = (const float*)d_in[2];
    const float* table  = (const float*)d_in[3];
    const float* Wm     = (const float*)d_in[4];
    const float* bm_    = (const float*)d_in[5];
    const float* Wv     = (const float*)d_in[6];
    const float* bv_    = (const float*)d_in[7];
    const float* Wl2r   = (const float*)d_in[8];
    const float* bl2r   = (const float*)d_in[9];
    const float* Wih0   = (const float*)d_in[10];
    const float* Whh0   = (const float*)d_in[11];
    const float* bih0   = (const float*)d_in[12];
    const float* bhh0   = (const float*)d_in[13];
    const float* Wih1   = (const float*)d_in[14];
    const float* Whh1   = (const float*)d_in[15];
    const float* bih1   = (const float*)d_in[16];
    const float* bhh1   = (const float*)d_in[17];
    const float* Wout   = (const float*)d_in[18];
    const float* bout   = (const float*)d_in[19];
    const float* lW1 = (const float*)d_in[20]; const float* lb1 = (const float*)d_in[21];
    const float* lW2 = (const float*)d_in[22]; const float* lb2 = (const float*)d_in[23];
    const float* lW3 = (const float*)d_in[24]; const float* lb3 = (const float*)d_in[25];
    const float* sW1 = (const float*)d_in[26]; const float* sb1 = (const float*)d_in[27];
    const float* sW2 = (const float*)d_in[28]; const float* sb2 = (const float*)d_in[29];
    const float* sW3 = (const float*)d_in[30]; const float* sb3 = (const float*)d_in[31];

    float* out = (float*)d_out;              // (B,S,V) = 2048 x 32000
    float* aux = out + 65536000;             // o_mean / o_std / o_z / o_logp / o_sas

    char* ws = (char*)d_ws;
    unsigned short* Woutb = (unsigned short*)ws;  ws += 32768000;  // 32000x512 bf16 (in-kernel cvt)
    unsigned short* Wih0b = (unsigned short*)ws;  ws += 393216;    // 1536x128 bf16
    unsigned short* embb  = (unsigned short*)ws;  ws += 524288;    // 2048x128 bf16
    float*          state = (float*)ws;           ws += 131072;    // 2x32x512
    float*          xW    = (float*)ws;           ws += 12582912;  // 2048x1536 f32 (in-kernel)
    unsigned short* out1x = (unsigned short*)ws;  ws += 2101248;   // 16 x (128x512 + 256B pad) bf16
    unsigned short* h0x   = (unsigned short*)ws;  ws += 131072;    // 2x32x512 f16
    unsigned short* h1x   = (unsigned short*)ws;  ws += 131072;
    unsigned short* o0x   = (unsigned short*)ws;  ws += 262144;    // 4x32x512 f16 (4-deep)
    int*            flgp  = (int*)ws;             ws += 65536;     // 16384 ints

    (void)hipMemsetAsync(flgp, 0, 65536, stream);

    // single persistent kernel: encoder + xW0 + 2-layer scan + shadow GEMM
    gru_fused_kernel<<<dim3(NWG_ALL), dim3(512), 0, stream>>>(
        tok, table, Wm, bm_, Wv, bv_, noise, Wl2r, bl2r,
        lW1, lb1, lW2, lb2, lW3, lb3, sW1, sb1, sW2, sb2, sW3, sb3,
        Wih0, bih0, Whh0, bhh0, Whh1, Wih1, bih1, bhh1, lens,
        Wout, bout, out, aux, embb, Wih0b, state, xW,
        h0x, h1x, o0x, out1x, Woutb, flgp);
}

// Round 16
// 347.113 us; speedup vs baseline: 1.0219x; 1.0219x over previous
//
#include <hip/hip_runtime.h>

// Frag2Mol: embed -> encoder(VAE) -> 2x GRU(scan over T=64) -> vocab GEMM.
// Sizes: B=32 S=64 V=32000 E=128 H=512 L=2 LAT=64.
// r16: REVERT to r14 (best: 347us). r15's single-kernel fold serialized the
//      encoder into the fused kernel's head (+50us). r14 structure: separate
//      embed/encoder launch; persistent kernel = xW0 producer (idle window)
//      + 2-layer pipelined scan (48 WGs) + shadow output GEMM (208 WGs).

typedef __attribute__((ext_vector_type(8))) short bf16x8_t;
typedef __attribute__((ext_vector_type(8))) unsigned short u16x8_t;
typedef __attribute__((ext_vector_type(4))) float f32x4_t;
typedef __attribute__((ext_vector_type(8))) _Float16 f16x8_t;
typedef __attribute__((ext_vector_type(4))) unsigned int u32x4_t;

#define AS_AGENT __HIP_MEMORY_SCOPE_AGENT

static __device__ __forceinline__ unsigned short f2bf(float f) {
    unsigned int u = __float_as_uint(f);
    u += 0x7fffu + ((u >> 16) & 1u);
    return (unsigned short)(u >> 16);
}
static __device__ __forceinline__ unsigned short bfround(unsigned int u) {
    u += 0x7fffu + ((u >> 16) & 1u);
    return (unsigned short)(u >> 16);
}
static __device__ __forceinline__ unsigned short f2h(float f) {
    _Float16 h = (_Float16)f;
    return __builtin_bit_cast(unsigned short, h);
}
static __device__ __forceinline__ float sigmoidf_(float x) {
    return 1.f / (1.f + __expf(-x));
}

// ---------------- merged: embed + Wih0 cvt + encoder ----------------
__global__ __launch_bounds__(256) void embed_encoder_kernel(
    const int* __restrict__ tok, const float* __restrict__ table,
    const float* __restrict__ Wih0f,
    const float* __restrict__ Wm, const float* __restrict__ bm,
    const float* __restrict__ Wv, const float* __restrict__ bv,
    const float* __restrict__ noise,
    const float* __restrict__ Wl2r, const float* __restrict__ bl2r,
    const float* __restrict__ lW1, const float* __restrict__ lb1,
    const float* __restrict__ lW2, const float* __restrict__ lb2,
    const float* __restrict__ lW3, const float* __restrict__ lb3,
    const float* __restrict__ sW1, const float* __restrict__ sb1,
    const float* __restrict__ sW2, const float* __restrict__ sb2,
    const float* __restrict__ sW3, const float* __restrict__ sb3,
    float* __restrict__ o_mean, float* __restrict__ o_std, float* __restrict__ o_z,
    float* __restrict__ o_logp, float* __restrict__ o_sas,
    float* __restrict__ state,
    unsigned short* __restrict__ embb,      // 2048x128 bf16
    unsigned short* __restrict__ Wih0b)     // 1536x128 bf16
{
    const int b = blockIdx.x, tid = threadIdx.x;
    __shared__ float v_[128], mn[64], sd[64], zz[2][64], hh1[200], hh2[100];
    if (tid < 128) {
        const int e = tid;
        float acc = 0.f;
        for (int s = 0; s < 64; ++s) {
            int id = tok[b * 64 + s];
            float v = table[(size_t)id * 128 + e];
            embb[(size_t)(b * 64 + s) * 128 + e] = f2bf(v);
            if (id > 2) acc += v;
        }
        v_[e] = acc;
    }
    for (int i = b * 256 + tid; i < 49152; i += 8192) {
        float4 v = reinterpret_cast<const float4*>(Wih0f)[i];
        ushort4 o;
        o.x = f2bf(v.x); o.y = f2bf(v.y); o.z = f2bf(v.z); o.w = f2bf(v.w);
        reinterpret_cast<ushort4*>(Wih0b)[i] = o;
    }
    __syncthreads();
    if (tid < 128) {
        int j = tid & 63;
        bool isv = tid >= 64;
        const float* W = (isv ? Wv : Wm) + j * 128;
        float a = isv ? bv[j] : bm[j];
#pragma unroll 4
        for (int k = 0; k < 128; ++k) a = fmaf(v_[k], W[k], a);
        if (!isv) { mn[j] = a; o_mean[b * 64 + j] = a; }
        else      { float s = __expf(0.5f * a); sd[j] = s; o_std[b * 64 + j] = s; }
    }
    __syncthreads();
    if (tid < 128) {
        int l = tid >> 6, j = tid & 63;
        float zv = fmaf(noise[(l * 32 + b) * 64 + j], sd[j], mn[j]);
        zz[l][j] = zv;
        o_z[(l * 32 + b) * 64 + j] = zv;
    }
    __syncthreads();
#pragma unroll
    for (int p = 0; p < 4; ++p) {
        int tt = p * 256 + tid;
        int l = tt >> 9, hd = tt & 511;
        const float* W = Wl2r + hd * 64;
        float a = bl2r[hd];
#pragma unroll 4
        for (int k = 0; k < 64; ++k) a = fmaf(zz[l][k], W[k], a);
        state[(size_t)(l * 32 + b) * 512 + hd] = a;
    }
    if (tid < 200) {
        const float* W = lW1 + tid * 64;
        float a = lb1[tid];
        for (int k = 0; k < 64; ++k) a = fmaf(mn[k], W[k], a);
        hh1[tid] = fmaxf(a, 0.f);
    }
    __syncthreads();
    if (tid < 100) {
        const float* W = lW2 + tid * 200;
        float a = lb2[tid];
        for (int k = 0; k < 200; ++k) a = fmaf(hh1[k], W[k], a);
        hh2[tid] = fmaxf(a, 0.f);
    }
    __syncthreads();
    if (tid == 0) {
        float a = lb3[0];
        for (int k = 0; k < 100; ++k) a = fmaf(hh2[k], lW3[k], a);
        o_logp[b] = a;
    }
    __syncthreads();
    if (tid < 200) {
        const float* W = sW1 + tid * 64;
        float a = sb1[tid];
        for (int k = 0; k < 64; ++k) a = fmaf(mn[k], W[k], a);
        hh1[tid] = fmaxf(a, 0.f);
    }
    __syncthreads();
    if (tid < 100) {
        const float* W = sW2 + tid * 200;
        float a = sb2[tid];
        for (int k = 0; k < 200; ++k) a = fmaf(hh1[k], W[k], a);
        hh2[tid] = fmaxf(a, 0.f);
    }
    __syncthreads();
    if (tid == 0) {
        float a = sb3[0];
        for (int k = 0; k < 100; ++k) a = fmaf(hh2[k], sW3[k], a);
        o_sas[b] = a;
    }
}

// ---------------- persistent 3-role kernel ----------------
// 256 WGs: wg<16 L0 scan; 16<=wg<48 L1 scan; wg>=48 output GEMM (shadow).
// GEMM role: (1) xW0 producer (192 tiles, bypass f32 stores, tile flags at
// flags[8192+g*16]); (2) JIT per-panel Wout cvt (panel flags 2048+n*16);
// (3) main loop: 4000 single-m tiles, gate 4m+6, A cached from padded
// out1x, nt output stores. L0: one-time 192-tile pre-poll before t=0 xW read.
#define NWG_L0 16
#define NWG_TOT 48
#define NWG_ALL 256
#define NWG_GEMM 208
#define OCH 32832   // out1x chunk stride in u32 (=65664 ushorts = 131328 B)

__global__ __launch_bounds__(512) void gru_fused_kernel(
    float* __restrict__ xW0,           // 2048 x 1536 f32 (produced in-kernel)
    const unsigned short* __restrict__ embb,   // 2048 x 128 bf16
    const unsigned short* __restrict__ Wih0b,  // 1536 x 128 bf16
    const float* __restrict__ bih0,    // 1536
    const float* __restrict__ Whh0, const float* __restrict__ bhh0,
    const float* __restrict__ Whh1, const float* __restrict__ Wih1,
    const float* __restrict__ bih1, const float* __restrict__ bhh1,
    const float* __restrict__ hinit,   // 2 x 32 x 512 (state)
    const int* __restrict__ lengths,   // 32
    unsigned short* __restrict__ h0x,  // 2 x 32 x 512 f16
    unsigned short* __restrict__ h1x,  // 2 x 32 x 512 f16
    unsigned short* __restrict__ o0x,  // 4 x 32 x 512 f16 (out0 exchange, 4-deep)
    unsigned short* __restrict__ out1x,// 16 chunks x (128x512 + pad) bf16 t-major
    const float* __restrict__ Woutf,   // 32000 x 512 f32
    unsigned short* __restrict__ Woutb,// 32000 x 512 bf16 (written in-kernel)
    const float* __restrict__ bout,    // 32000
    float* __restrict__ outp,          // (B,S,V) f32
    int* __restrict__ flags)           // 16384 ints (zeroed)
{
    __shared__ __align__(16) char smem[157184];
    const int tid = threadIdx.x;
    const int wg = blockIdx.x;
    const int lane = tid & 63;
    const int wave = tid >> 6;                // 0..7
    unsigned int* __restrict__ h0x32 = (unsigned int*)h0x;
    unsigned int* __restrict__ h1x32 = (unsigned int*)h1x;
    unsigned int* __restrict__ o0x32 = (unsigned int*)o0x;
    unsigned int* __restrict__ o1x32 = (unsigned int*)out1x;

    // defensive agent-acquire: drop any stale/poison L2 lines at kernel start
    (void)__hip_atomic_load(&flags[0], __ATOMIC_ACQUIRE, AS_AGENT);

    if (wg >= NWG_TOT) {
        // ================= GEMM role =================
        unsigned short* lA = (unsigned short*)smem;            // 128 x 64 bf16
        unsigned short* lB = (unsigned short*)(smem + 16384);  // 128 x 64 bf16
        const int g = wg - NWG_TOT;            // 0..207
        const int wm = wave >> 2;              // 0..1 (64-row m half)
        const int wn = wave & 3;               // 0..3 (32-col n quad)

        // ---- (1) xW0 producer: tile (pm, pn) of xW = embb @ Wih0b^T + bih0 ----
        if (g < 192) {
            const int pm = g / 12, pn = g % 12;
            f32x4_t pacc[4][2];
#pragma unroll
            for (int i = 0; i < 4; ++i)
#pragma unroll
                for (int j = 0; j < 2; ++j) pacc[i][j] = (f32x4_t){0.f, 0.f, 0.f, 0.f};
            for (int kt = 0; kt < 128; kt += 64) {
#pragma unroll
                for (int p = 0; p < 2; ++p) {
                    int gi = p * 512 + tid;
                    int row = gi >> 3, c8 = gi & 7;
                    int dst = row * 64 + ((c8 ^ (row & 7)) << 3);
                    *(u32x4_t*)&lA[dst] = *(const u32x4_t*)(embb +
                        (size_t)(pm * 128 + row) * 128 + kt + (c8 << 3));
                    *(u32x4_t*)&lB[dst] = *(const u32x4_t*)(Wih0b +
                        (size_t)(pn * 128 + row) * 128 + kt + (c8 << 3));
                }
                __syncthreads();
#pragma unroll
                for (int kc = 0; kc < 2; ++kc) {
                    int c8 = kc * 4 + (lane >> 4);
                    bf16x8_t af[4], bfr[2];
#pragma unroll
                    for (int i = 0; i < 4; ++i) {
                        int ra = wm * 64 + i * 16 + (lane & 15);
                        af[i] = *(const bf16x8_t*)&lA[ra * 64 + ((c8 ^ (ra & 7)) << 3)];
                    }
#pragma unroll
                    for (int j = 0; j < 2; ++j) {
                        int rb = wn * 32 + j * 16 + (lane & 15);
                        bfr[j] = *(const bf16x8_t*)&lB[rb * 64 + ((c8 ^ (rb & 7)) << 3)];
                    }
#pragma unroll
                    for (int i = 0; i < 4; ++i)
#pragma unroll
                        for (int j = 0; j < 2; ++j)
                            pacc[i][j] = __builtin_amdgcn_mfma_f32_16x16x32_bf16(
                                af[i], bfr[j], pacc[i][j], 0, 0, 0);
                }
                __syncthreads();
            }
            // epilogue: bypass f32 stores (cross-XCD visible at L3)
            const int lm = (lane >> 4) * 4, ln = lane & 15;
#pragma unroll
            for (int i = 0; i < 4; ++i) {
#pragma unroll
                for (int j = 0; j < 2; ++j) {
                    int gn = pn * 128 + wn * 32 + j * 16 + ln;
                    float bb_ = bih0[gn];
#pragma unroll
                    for (int r = 0; r < 4; ++r) {
                        int gm = pm * 128 + wm * 64 + i * 16 + lm + r;
                        __hip_atomic_store(&xW0[(size_t)gm * 1536 + gn],
                                           pacc[i][j][r] + bb_, __ATOMIC_RELAXED, AS_AGENT);
                    }
                }
            }
            asm volatile("s_waitcnt vmcnt(0)" ::: "memory");
            __syncthreads();
            if (tid == 0)
                __hip_atomic_store(&flags[8192 + g * 16], 1, __ATOMIC_RELAXED, AS_AGENT);
        }

        // ---- (2) JIT cvt: WG g converts its own panels (n = g, g+208<250) ----
        for (int pn = g; pn < 250; pn += NWG_GEMM) {
            const u32x4_t* src = (const u32x4_t*)Woutf + (size_t)pn * 16384;
            unsigned long long* dst = (unsigned long long*)Woutb + (size_t)pn * 16384;
            for (int i = tid; i < 16384; i += 512) {
                u32x4_t q = __builtin_nontemporal_load(src + i);   // read-once: nt
                unsigned int lo = (unsigned int)bfround(q[0]) | ((unsigned int)bfround(q[1]) << 16);
                unsigned int hi = (unsigned int)bfround(q[2]) | ((unsigned int)bfround(q[3]) << 16);
                unsigned long long w = (unsigned long long)lo | ((unsigned long long)hi << 32);
                __hip_atomic_store(dst + i, w, __ATOMIC_RELAXED, AS_AGENT);  // bypass
            }
            asm volatile("s_waitcnt vmcnt(0)" ::: "memory");
            __syncthreads();
            if (tid == 0)
                __hip_atomic_store(&flags[2048 + pn * 16], 1, __ATOMIC_RELAXED, AS_AGENT);
        }

        // ---- (3) main loop: single-m tiles ----
        int mPrev = -1;
        for (int T = g; T < 4000; T += NWG_GEMM) {
            const int m = T / 250, n = T % 250;
            if (m != mPrev) {
                if (wave == 0) {
                    const int tgt = 4 * m + 6;   // L1 finished t1 <= 4m+3
                    for (;;) {
                        int v = 0x40000000;
                        if (lane < 32)
                            v = __hip_atomic_load(&flags[(NWG_L0 + lane) << 5],
                                                  __ATOMIC_RELAXED, AS_AGENT);
                        if (__all(v >= tgt)) break;
                        __builtin_amdgcn_s_sleep(8);
                    }
                }
                mPrev = m;
            }
            // panel-ready gate (first consumer == converter, so ~never spins)
            if (wave == 0) {
                while (__hip_atomic_load(&flags[2048 + n * 16], __ATOMIC_RELAXED, AS_AGENT) < 1)
                    __builtin_amdgcn_s_sleep(8);
            }
            __syncthreads();

            f32x4_t acc[4][2];
#pragma unroll
            for (int i = 0; i < 4; ++i)
#pragma unroll
                for (int j = 0; j < 2; ++j) acc[i][j] = (f32x4_t){0.f, 0.f, 0.f, 0.f};

            for (int kt = 0; kt < 512; kt += 64) {
#pragma unroll
                for (int p = 0; p < 2; ++p) {
                    int gi = p * 512 + tid;
                    int row = gi >> 3, c8 = gi & 7;
                    int dst = row * 64 + ((c8 ^ (row & 7)) << 3);
                    u32x4_t qa = *(const u32x4_t*)(out1x + (size_t)m * 65664 +
                                                   row * 512 + kt + (c8 << 3));
                    u32x4_t qb = *(const u32x4_t*)(Woutb + ((size_t)(n * 128 + row)) * 512 +
                                                   kt + (c8 << 3));
                    *(u32x4_t*)&lA[dst] = qa;
                    *(u32x4_t*)&lB[dst] = qb;
                }
                __syncthreads();
#pragma unroll
                for (int kc = 0; kc < 2; ++kc) {
                    bf16x8_t af[4], bfr[2];
                    int c8 = kc * 4 + (lane >> 4);
#pragma unroll
                    for (int i = 0; i < 4; ++i) {
                        int ra = wm * 64 + i * 16 + (lane & 15);
                        af[i] = *(const bf16x8_t*)&lA[ra * 64 + ((c8 ^ (ra & 7)) << 3)];
                    }
#pragma unroll
                    for (int j = 0; j < 2; ++j) {
                        int rb = wn * 32 + j * 16 + (lane & 15);
                        bfr[j] = *(const bf16x8_t*)&lB[rb * 64 + ((c8 ^ (rb & 7)) << 3)];
                    }
#pragma unroll
                    for (int i = 0; i < 4; ++i)
#pragma unroll
                        for (int j = 0; j < 2; ++j)
                            acc[i][j] = __builtin_amdgcn_mfma_f32_16x16x32_bf16(
                                af[i], bfr[j], acc[i][j], 0, 0, 0);
                }
                __syncthreads();
            }
            // epilogue: nt (no-allocate) stores -- output is write-once
            const int lm = (lane >> 4) * 4, ln = lane & 15;
#pragma unroll
            for (int i = 0; i < 4; ++i) {
                int rl0 = wm * 64 + i * 16 + lm;
#pragma unroll
                for (int j = 0; j < 2; ++j) {
                    int gn = n * 128 + wn * 32 + j * 16 + ln;
                    float bb = bout[gn];
#pragma unroll
                    for (int r = 0; r < 4; ++r) {
                        int rl = rl0 + r;
                        int t = 4 * m + (rl >> 5), b = rl & 31;
                        __builtin_nontemporal_store(acc[i][j][r] + bb,
                            &outp[(size_t)(b * 64 + t) * 32000 + gn]);
                    }
                }
            }
        }
        return;
    }

    // ================= scan roles =================
    unsigned short* Wl = (unsigned short*)smem;             // 96 KB f16 B-fragments
    u32x4_t* hstage4 = (u32x4_t*)(smem + 98304);            // 32 KB gather stage
    float* csm = (float*)(smem + 131072);                   // [2][3][32][34]
#define CSM(p, gt, b, c) csm[((((p)*3 + (gt)) * 32 + (b)) * 34) + (c)]
    const int gate = wave >> 1;         // 0=r 1=z 2=n (waves 0..5)
    const int mt = wave & 1;            // M-tile (batches 0-15 / 16-31)

    if (wg < NWG_L0) {
        // ================= L0 role: d-slice 32 =================
        const int d0 = wg * 32;
        for (int idx = tid; idx < 6144; idx += 512) {
            int ln = idx & 63, kk = (idx >> 6) & 15, nt = (idx >> 10) & 1, g_ = idx >> 11;
            int grow = g_ * 512 + d0 + nt * 16 + (ln & 15);
            int k = kk * 32 + ((ln >> 4) << 3);
            const float* src = Whh0 + (size_t)grow * 512 + k;
            f16x8_t v;
#pragma unroll
            for (int j = 0; j < 8; ++j) v[j] = (_Float16)src[j];
            *(f16x8_t*)&Wl[idx << 3] = v;
        }
        const int ub = tid >> 4, dpl = (tid & 15) * 2, ud = d0 + dpl;
        float h_lo = hinit[(size_t)ub * 512 + ud];
        float h_hi = hinit[(size_t)ub * 512 + ud + 1];
        const float br_lo = bhh0[ud],        br_hi = bhh0[ud + 1];
        const float bz_lo = bhh0[512 + ud],  bz_hi = bhh0[512 + ud + 1];
        const float bn_lo = bhh0[1024 + ud], bn_hi = bhh0[1024 + ud + 1];
        const int lenb = lengths[ub];
        {   // init publish h0 -> h0x[0]
            unsigned int hw = (unsigned int)f2h(h_lo) | ((unsigned int)f2h(h_hi) << 16);
            __hip_atomic_store(&h0x32[ub * 256 + (ud >> 1)], hw, __ATOMIC_RELAXED, AS_AGENT);
        }
        asm volatile("s_waitcnt vmcnt(0)" ::: "memory");
        __syncthreads();
        if (tid == 0) __hip_atomic_store(&flags[wg << 5], 1, __ATOMIC_RELAXED, AS_AGENT);

        // one-time pre-poll: all 192 xW0 tiles published
        if (wave == 0) {
            for (;;) {
                int mnv = 1;
#pragma unroll
                for (int bb = 0; bb < 3; ++bb) {
                    int idx = bb * 64 + lane;
                    if (idx < 192) {
                        int v = __hip_atomic_load(&flags[8192 + idx * 16],
                                                  __ATOMIC_RELAXED, AS_AGENT);
                        mnv = v < mnv ? v : mnv;
                    }
                }
                if (__all(mnv >= 1)) break;
                __builtin_amdgcn_s_sleep(2);
            }
        }
        __syncthreads();

        // xW0 prefetch for t=0 (safe: producers drained before tile flags)
        const float* xrow = xW0 + (size_t)(ub * 64) * 1536 + ud;
        float2 px_r = *(const float2*)(xrow);
        float2 px_z = *(const float2*)(xrow + 512);
        float2 px_n = *(const float2*)(xrow + 1024);

        for (int r = 0; r < 64; ++r) {
            // decoupled poll: own group at r+1; L1 only at r-2 (o0x slot WAR)
            if (wave == 0) {
                for (;;) {
                    int v = 0x40000000;
                    int tgt = (lane < NWG_L0) ? (r + 1) : (r - 2);
                    if (lane < NWG_TOT)
                        v = __hip_atomic_load(&flags[lane << 5], __ATOMIC_RELAXED, AS_AGENT);
                    else
                        tgt = 0;
                    if (__all(v >= tgt)) break;
                    __builtin_amdgcn_s_sleep(1);
                }
            }
            __syncthreads();
            // gather h0x[r&1] -> stage
            {
                const char* srcb = (const char*)h0x + ((r & 1) << 15);
                u32x4_t q0, q1, q2, q3;
                asm volatile("global_load_dwordx4 %0, %1, off sc0 sc1"
                             : "=v"(q0) : "v"(srcb + ((size_t)tid << 4)) : "memory");
                asm volatile("global_load_dwordx4 %0, %1, off sc0 sc1"
                             : "=v"(q1) : "v"(srcb + ((size_t)(512 + tid) << 4)) : "memory");
                asm volatile("global_load_dwordx4 %0, %1, off sc0 sc1"
                             : "=v"(q2) : "v"(srcb + ((size_t)(1024 + tid) << 4)) : "memory");
                asm volatile("global_load_dwordx4 %0, %1, off sc0 sc1"
                             : "=v"(q3) : "v"(srcb + ((size_t)(1536 + tid) << 4)) : "memory");
                asm volatile("s_waitcnt vmcnt(0)" ::: "memory");
                int g0 = tid, g1 = 512 + tid, g2 = 1024 + tid, g3 = 1536 + tid;
                hstage4[g0 ^ ((g0 >> 6) & 7)] = q0;
                hstage4[g1 ^ ((g1 >> 6) & 7)] = q1;
                hstage4[g2 ^ ((g2 >> 6) & 7)] = q2;
                hstage4[g3 ^ ((g3 >> 6) & 7)] = q3;
            }
            __syncthreads();
            if (wave < 6) {
                const int brow = mt * 16 + (lane & 15);
                const int ko = lane >> 4;
                f32x4_t acc0 = (f32x4_t){0.f, 0.f, 0.f, 0.f};
                f32x4_t acc1 = (f32x4_t){0.f, 0.f, 0.f, 0.f};
#pragma unroll
                for (int kk = 0; kk < 16; ++kk) {
                    int gg = brow * 64 + kk * 4 + ko;
                    f16x8_t af = __builtin_bit_cast(f16x8_t, hstage4[gg ^ (brow & 7)]);
                    f16x8_t bf0 = *(const f16x8_t*)&Wl[(((gate * 2 + 0) * 16 + kk) * 64 + lane) << 3];
                    f16x8_t bf1 = *(const f16x8_t*)&Wl[(((gate * 2 + 1) * 16 + kk) * 64 + lane) << 3];
                    acc0 = __builtin_amdgcn_mfma_f32_16x16x32_f16(af, bf0, acc0, 0, 0, 0);
                    acc1 = __builtin_amdgcn_mfma_f32_16x16x32_f16(af, bf1, acc1, 0, 0, 0);
                }
                const int crow = mt * 16 + ((lane >> 4) << 2), ccol = lane & 15;
#pragma unroll
                for (int rr = 0; rr < 4; ++rr) {
                    CSM(0, gate, crow + rr, ccol) = acc0[rr];
                    CSM(0, gate, crow + rr, 16 + ccol) = acc1[rr];
                }
            }
            __syncthreads();
            // gate update
            unsigned int ow = 0u;
            if (r < lenb) {
                float hr_lo = CSM(0, 0, ub, dpl), hr_hi = CSM(0, 0, ub, dpl + 1);
                float hz_lo = CSM(0, 1, ub, dpl), hz_hi = CSM(0, 1, ub, dpl + 1);
                float hn_lo = CSM(0, 2, ub, dpl), hn_hi = CSM(0, 2, ub, dpl + 1);
                float r0 = sigmoidf_(px_r.x + hr_lo + br_lo);
                float r1 = sigmoidf_(px_r.y + hr_hi + br_hi);
                float u0 = sigmoidf_(px_z.x + hz_lo + bz_lo);
                float u1 = sigmoidf_(px_z.y + hz_hi + bz_hi);
                float n0 = tanhf(px_n.x + r0 * (hn_lo + bn_lo));
                float n1 = tanhf(px_n.y + r1 * (hn_hi + bn_hi));
                h_lo = (1.f - u0) * n0 + u0 * h_lo;
                h_hi = (1.f - u1) * n1 + u1 * h_hi;
                ow = (unsigned int)f2h(h_lo) | ((unsigned int)f2h(h_hi) << 16);
            }
            // publish h0_{t+1} and out0[t] (o0x slot r&3, 4-deep)
            {
                unsigned int hw = (unsigned int)f2h(h_lo) | ((unsigned int)f2h(h_hi) << 16);
                __hip_atomic_store(&h0x32[((r + 1) & 1) * 8192 + ub * 256 + (ud >> 1)],
                                   hw, __ATOMIC_RELAXED, AS_AGENT);
                __hip_atomic_store(&o0x32[(r & 3) * 8192 + ub * 256 + (ud >> 1)],
                                   ow, __ATOMIC_RELAXED, AS_AGENT);
            }
            asm volatile("s_waitcnt vmcnt(0)" ::: "memory");
            __syncthreads();
            if (tid == 0) __hip_atomic_store(&flags[wg << 5], r + 2, __ATOMIC_RELAXED, AS_AGENT);
            // off-chain: xW0 prefetch for t=r+1
            {
                int tn = r + 1 < 64 ? r + 1 : 63;
                const float* xp = xW0 + (size_t)(ub * 64 + tn) * 1536 + ud;
                px_r = *(const float2*)(xp);
                px_z = *(const float2*)(xp + 512);
                px_n = *(const float2*)(xp + 1024);
            }
        }
    } else {
        // ================= L1 role: d-slice 16, K=1024 =================
        const int lid = wg - NWG_L0;
        const int d0 = lid * 16;
        for (int idx = tid; idx < 6144; idx += 512) {
            int ln = idx & 63, kk = (idx >> 6) & 31, g_ = idx >> 11;
            int grow = g_ * 512 + d0 + (ln & 15);
            int k = (kk & 15) * 32 + ((ln >> 4) << 3);
            const float* src = (kk < 16 ? Whh1 : Wih1) + (size_t)grow * 512 + k;
            f16x8_t v;
#pragma unroll
            for (int j = 0; j < 8; ++j) v[j] = (_Float16)src[j];
            *(f16x8_t*)&Wl[idx << 3] = v;
        }
        const bool upd = (tid < 256);
        const int ub = tid >> 3, dpl = (tid & 7) * 2, ud = d0 + dpl;
        float h_lo = 0.f, h_hi = 0.f;
        float br_lo = 0.f, br_hi = 0.f, bz_lo = 0.f, bz_hi = 0.f;
        float bxn_lo = 0.f, bxn_hi = 0.f, bhn_lo = 0.f, bhn_hi = 0.f;
        int lenb = 0;
        if (upd) {
            h_lo = hinit[16384 + (size_t)ub * 512 + ud];
            h_hi = hinit[16384 + (size_t)ub * 512 + ud + 1];
            br_lo = bih1[ud] + bhh1[ud];
            br_hi = bih1[ud + 1] + bhh1[ud + 1];
            bz_lo = bih1[512 + ud] + bhh1[512 + ud];
            bz_hi = bih1[512 + ud + 1] + bhh1[512 + ud + 1];
            bxn_lo = bih1[1024 + ud];   bxn_hi = bih1[1024 + ud + 1];
            bhn_lo = bhh1[1024 + ud];   bhn_hi = bhh1[1024 + ud + 1];
            lenb = lengths[ub];
            // init publish h1 -> h1x[1] (round 1 reads parity 1)
            unsigned int hw = (unsigned int)f2h(h_lo) | ((unsigned int)f2h(h_hi) << 16);
            __hip_atomic_store(&h1x32[8192 + ub * 256 + (ud >> 1)], hw, __ATOMIC_RELAXED, AS_AGENT);
        }
        asm volatile("s_waitcnt vmcnt(0)" ::: "memory");
        __syncthreads();
        if (tid == 0) __hip_atomic_store(&flags[wg << 5], 2, __ATOMIC_RELAXED, AS_AGENT);

        for (int r = 1; r <= 64; ++r) {
            const int t1 = r - 1;
            if (wave == 0) {
                const int tgt = r + 1;
                for (;;) {
                    int v = 0x40000000;
                    if (lane < NWG_TOT)
                        v = __hip_atomic_load(&flags[lane << 5], __ATOMIC_RELAXED, AS_AGENT);
                    if (__all(v >= tgt)) break;
                    __builtin_amdgcn_s_sleep(1);
                }
            }
            __syncthreads();
            // gather: h1 first (4 loads), then out0 slot t1&3 (4 loads)
            u32x4_t a0, a1, a2, a3, b0, b1, b2, b3;
            {
                const char* sh = (const char*)h1x + ((r & 1) << 15);
                const char* so = (const char*)o0x + ((t1 & 3) << 15);
                asm volatile("global_load_dwordx4 %0, %1, off sc0 sc1"
                             : "=v"(a0) : "v"(sh + ((size_t)tid << 4)) : "memory");
                asm volatile("global_load_dwordx4 %0, %1, off sc0 sc1"
                             : "=v"(a1) : "v"(sh + ((size_t)(512 + tid) << 4)) : "memory");
                asm volatile("global_load_dwordx4 %0, %1, off sc0 sc1"
                             : "=v"(a2) : "v"(sh + ((size_t)(1024 + tid) << 4)) : "memory");
                asm volatile("global_load_dwordx4 %0, %1, off sc0 sc1"
                             : "=v"(a3) : "v"(sh + ((size_t)(1536 + tid) << 4)) : "memory");
                asm volatile("global_load_dwordx4 %0, %1, off sc0 sc1"
                             : "=v"(b0) : "v"(so + ((size_t)tid << 4)) : "memory");
                asm volatile("global_load_dwordx4 %0, %1, off sc0 sc1"
                             : "=v"(b1) : "v"(so + ((size_t)(512 + tid) << 4)) : "memory");
                asm volatile("global_load_dwordx4 %0, %1, off sc0 sc1"
                             : "=v"(b2) : "v"(so + ((size_t)(1024 + tid) << 4)) : "memory");
                asm volatile("global_load_dwordx4 %0, %1, off sc0 sc1"
                             : "=v"(b3) : "v"(so + ((size_t)(1536 + tid) << 4)) : "memory");
                asm volatile("s_waitcnt vmcnt(4)" ::: "memory");  // h1 done
                int g0 = tid, g1 = 512 + tid, g2 = 1024 + tid, g3 = 1536 + tid;
                hstage4[g0 ^ ((g0 >> 6) & 7)] = a0;
                hstage4[g1 ^ ((g1 >> 6) & 7)] = a1;
                hstage4[g2 ^ ((g2 >> 6) & 7)] = a2;
                hstage4[g3 ^ ((g3 >> 6) & 7)] = a3;
            }
            __syncthreads();
            // pass 0: acc_h = h1 @ Whh1^T (one 16x16 tile per wave)
            f32x4_t acc_h = (f32x4_t){0.f, 0.f, 0.f, 0.f};
            const int brow = mt * 16 + (lane & 15);
            const int ko = lane >> 4;
            if (wave < 6) {
#pragma unroll
                for (int kk = 0; kk < 16; ++kk) {
                    int gg = brow * 64 + kk * 4 + ko;
                    f16x8_t af = __builtin_bit_cast(f16x8_t, hstage4[gg ^ (brow & 7)]);
                    f16x8_t bf = *(const f16x8_t*)&Wl[(((gate * 32 + kk) * 64 + lane)) << 3];
                    acc_h = __builtin_amdgcn_mfma_f32_16x16x32_f16(af, bf, acc_h, 0, 0, 0);
                }
            }
            __syncthreads();  // all reads of h1 stage done
            {
                asm volatile("s_waitcnt vmcnt(0)" ::: "memory");  // out0 done
                int g0 = tid, g1 = 512 + tid, g2 = 1024 + tid, g3 = 1536 + tid;
                hstage4[g0 ^ ((g0 >> 6) & 7)] = b0;
                hstage4[g1 ^ ((g1 >> 6) & 7)] = b1;
                hstage4[g2 ^ ((g2 >> 6) & 7)] = b2;
                hstage4[g3 ^ ((g3 >> 6) & 7)] = b3;
            }
            __syncthreads();
            // pass 1: acc_x = out0 @ Wih1^T
            if (wave < 6) {
                f32x4_t acc_x = (f32x4_t){0.f, 0.f, 0.f, 0.f};
#pragma unroll
                for (int kk = 0; kk < 16; ++kk) {
                    int gg = brow * 64 + kk * 4 + ko;
                    f16x8_t af = __builtin_bit_cast(f16x8_t, hstage4[gg ^ (brow & 7)]);
                    f16x8_t bf = *(const f16x8_t*)&Wl[(((gate * 32 + 16 + kk) * 64 + lane)) << 3];
                    acc_x = __builtin_amdgcn_mfma_f32_16x16x32_f16(af, bf, acc_x, 0, 0, 0);
                }
                const int crow = mt * 16 + ((lane >> 4) << 2), ccol = lane & 15;
#pragma unroll
                for (int rr = 0; rr < 4; ++rr) {
                    CSM(0, gate, crow + rr, ccol) = acc_h[rr];
                    CSM(1, gate, crow + rr, ccol) = acc_x[rr];
                }
            }
            __syncthreads();
            // gate update (n-gate: x-part and h-part kept separate)
            unsigned int ow = 0u;
            if (upd) {
                if (t1 < lenb) {
                    float hr_lo = CSM(0, 0, ub, dpl), hr_hi = CSM(0, 0, ub, dpl + 1);
                    float hz_lo = CSM(0, 1, ub, dpl), hz_hi = CSM(0, 1, ub, dpl + 1);
                    float hn_lo = CSM(0, 2, ub, dpl), hn_hi = CSM(0, 2, ub, dpl + 1);
                    float xr_lo = CSM(1, 0, ub, dpl), xr_hi = CSM(1, 0, ub, dpl + 1);
                    float xz_lo = CSM(1, 1, ub, dpl), xz_hi = CSM(1, 1, ub, dpl + 1);
                    float xn_lo = CSM(1, 2, ub, dpl), xn_hi = CSM(1, 2, ub, dpl + 1);
                    float r0 = sigmoidf_(xr_lo + hr_lo + br_lo);
                    float r1 = sigmoidf_(xr_hi + hr_hi + br_hi);
                    float u0 = sigmoidf_(xz_lo + hz_lo + bz_lo);
                    float u1 = sigmoidf_(xz_hi + hz_hi + bz_hi);
                    float n0 = tanhf(xn_lo + bxn_lo + r0 * (hn_lo + bhn_lo));
                    float n1 = tanhf(xn_hi + bxn_hi + r1 * (hn_hi + bhn_hi));
                    h_lo = (1.f - u0) * n0 + u0 * h_lo;
                    h_hi = (1.f - u1) * n1 + u1 * h_hi;
                    ow = (unsigned int)f2bf(h_lo) | ((unsigned int)f2bf(h_hi) << 16);
                }
                if (r < 64) {
                    unsigned int hw = (unsigned int)f2h(h_lo) | ((unsigned int)f2h(h_hi) << 16);
                    __hip_atomic_store(&h1x32[((r + 1) & 1) * 8192 + ub * 256 + (ud >> 1)],
                                       hw, __ATOMIC_RELAXED, AS_AGENT);
                }
                // out1 publish: padded t-major bf16 chunks, bypass, pre-drain
                __hip_atomic_store(&o1x32[(size_t)(t1 >> 2) * OCH +
                                          ((t1 & 3) * 32 + ub) * 256 + (ud >> 1)],
                                   ow, __ATOMIC_RELAXED, AS_AGENT);
            }
            asm volatile("s_waitcnt vmcnt(0)" ::: "memory");
            __syncthreads();
            if (tid == 0)
                __hip_atomic_store(&flags[wg << 5], r + 2, __ATOMIC_RELAXED, AS_AGENT);
        }
    }
#undef CSM
}

extern "C" void kernel_launch(void* const* d_in, const int* in_sizes, int n_in,
                              void* d_out, int out_size, void* d_ws, size_t ws_size,
                              hipStream_t stream) {
    const int*   tok    = (const int*)d_in[0];
    const int*   lens   = (const int*)d_in[1];
    const float* noise  = (const float*)d_in[2];
    const float* table  = (const float*)d_in[3];
    const float* Wm     = (const float*)d_in[4];
    const float* bm_    = (const float*)d_in[5];
    const float* Wv     = (const float*)d_in[6];
    const float* bv_    = (const float*)d_in[7];
    const float* Wl2r   = (const float*)d_in[8];
    const float* bl2r   = (const float*)d_in[9];
    const float* Wih0   = (const float*)d_in[10];
    const float* Whh0   = (const float*)d_in[11];
    const float* bih0   = (const float*)d_in[12];
    const float* bhh0   = (const float*)d_in[13];
    const float* Wih1   = (const float*)d_in[14];
    const float* Whh1   = (const float*)d_in[15];
    const float* bih1   = (const float*)d_in[16];
    const float* bhh1   = (const float*)d_in[17];
    const float* Wout   = (const float*)d_in[18];
    const float* bout   = (const float*)d_in[19];
    const float* lW1 = (const float*)d_in[20]; const float* lb1 = (const float*)d_in[21];
    const float* lW2 = (const float*)d_in[22]; const float* lb2 = (const float*)d_in[23];
    const float* lW3 = (const float*)d_in[24]; const float* lb3 = (const float*)d_in[25];
    const float* sW1 = (const float*)d_in[26]; const float* sb1 = (const float*)d_in[27];
    const float* sW2 = (const float*)d_in[28]; const float* sb2 = (const float*)d_in[29];
    const float* sW3 = (const float*)d_in[30]; const float* sb3 = (const float*)d_in[31];

    float* out    = (float*)d_out;           // (B,S,V) = 2048 x 32000
    float* o_mean = out + 65536000;
    float* o_std  = o_mean + 2048;
    float* o_z    = o_std + 2048;
    float* o_logp = o_z + 4096;
    float* o_sas  = o_logp + 32;

    char* ws = (char*)d_ws;
    unsigned short* Woutb = (unsigned short*)ws;  ws += 32768000;  // 32000x512 bf16 (in-kernel cvt)
    unsigned short* Wih0b = (unsigned short*)ws;  ws += 393216;    // 1536x128 bf16
    unsigned short* embb  = (unsigned short*)ws;  ws += 524288;    // 2048x128 bf16
    float*          state = (float*)ws;           ws += 131072;    // 2x32x512
    float*          xW    = (float*)ws;           ws += 12582912;  // 2048x1536 f32 (in-kernel)
    unsigned short* out1x = (unsigned short*)ws;  ws += 2101248;   // 16 x (128x512 + 256B pad) bf16
    unsigned short* h0x   = (unsigned short*)ws;  ws += 131072;    // 2x32x512 f16
    unsigned short* h1x   = (unsigned short*)ws;  ws += 131072;
    unsigned short* o0x   = (unsigned short*)ws;  ws += 262144;    // 4x32x512 f16 (4-deep)
    int*            flgp  = (int*)ws;             ws += 65536;     // 16384 ints: WG/panel/tile flags

    (void)hipMemsetAsync(flgp, 0, 65536, stream);

    // embed + Wih0 cvt + encoder (one launch)
    embed_encoder_kernel<<<dim3(32), dim3(256), 0, stream>>>(
        tok, table, Wih0, Wm, bm_, Wv, bv_, noise, Wl2r, bl2r,
        lW1, lb1, lW2, lb2, lW3, lb3, sW1, sb1, sW2, sb2, sW3, sb3,
        o_mean, o_std, o_z, o_logp, o_sas, state, embb, Wih0b);

    // persistent 3-role kernel (xW0 production + scan + shadow GEMM)
    gru_fused_kernel<<<dim3(NWG_ALL), dim3(512), 0, stream>>>(
        xW, embb, Wih0b, bih0, Whh0, bhh0, Whh1, Wih1, bih1, bhh1, state, lens,
        h0x, h1x, o0x, out1x, Wout, Woutb, bout, out, flgp);
}